// Round 1
// baseline (245.910 us; speedup 1.0000x reference)
//
#include <hip/hip_runtime.h>
#include <math.h>

#define BROWS 16384
#define FEAT  128
#define KS    768
#define KT    1024
#define BM    128
#define KB    32

__device__ __forceinline__ void fma4(float4& a, float s, const float4& w) {
    a.x = fmaf(s, w.x, a.x);
    a.y = fmaf(s, w.y, a.y);
    a.z = fmaf(s, w.z, a.z);
    a.w = fmaf(s, w.w, a.w);
}

// One launch covers both GEMMs: blocks [0,128) do z_s = f_s@W_s.T + b_s,
// blocks [128,256) do z_t. 256 threads, BM=128 rows x 128 cols per block.
// Per-thread: 8 rows (strided 16) x 8 cols (cg*4 and 64+cg*4).
__global__ __launch_bounds__(256) void gemm_embed(
    const float* __restrict__ f_s, const float* __restrict__ Ws, const float* __restrict__ bs,
    const float* __restrict__ f_t, const float* __restrict__ Wt, const float* __restrict__ bt,
    float* __restrict__ z_s, float* __restrict__ z_t)
{
    __shared__ float sF[BM][KB + 4];   // row stride 36 floats (144B): 16B-aligned, bank = 4*row%32
    __shared__ float sW[KB][FEAT];     // k-major: col reads contiguous

    int bid = blockIdx.x;
    const float *f, *W, *bias;
    float* z;
    int K;
    if (bid < 128) { f = f_s; W = Ws; bias = bs; z = z_s; K = KS; }
    else           { f = f_t; W = Wt; bias = bt; z = z_t; K = KT; bid -= 128; }

    const int row0 = bid * BM;
    const int tid  = threadIdx.x;
    const int cg   = tid & 15;    // 16 col groups
    const int rg   = tid >> 4;    // 16 row groups; thread rows = rg + 16*i
    const int cg4  = cg * 4;

    float4 acc0[8], acc1[8];
    #pragma unroll
    for (int i = 0; i < 8; ++i) {
        acc0[i] = make_float4(0.f, 0.f, 0.f, 0.f);
        acc1[i] = make_float4(0.f, 0.f, 0.f, 0.f);
    }

    const int srow  = tid >> 1;   // f-staging row 0..127
    const int shalf = tid & 1;    // which 16-k half
    const int wcol  = tid >> 1;   // W-staging col 0..127

    for (int k0 = 0; k0 < K; k0 += KB) {
        // issue global loads before the barrier (overlap with prior compute drain)
        const float4* fg = (const float4*)(f + (size_t)(row0 + srow) * K + k0 + shalf * 16);
        float4 a0 = fg[0], a1 = fg[1], a2 = fg[2], a3 = fg[3];
        const float4* wg = (const float4*)(W + (size_t)wcol * K + k0 + shalf * 16);
        float4 b0 = wg[0], b1 = wg[1], b2 = wg[2], b3 = wg[3];

        __syncthreads();  // previous tile fully consumed

        float4* fdst = (float4*)&sF[srow][shalf * 16];
        fdst[0] = a0; fdst[1] = a1; fdst[2] = a2; fdst[3] = a3;

        const int kbase = shalf * 16;
        sW[kbase +  0][wcol] = b0.x; sW[kbase +  1][wcol] = b0.y;
        sW[kbase +  2][wcol] = b0.z; sW[kbase +  3][wcol] = b0.w;
        sW[kbase +  4][wcol] = b1.x; sW[kbase +  5][wcol] = b1.y;
        sW[kbase +  6][wcol] = b1.z; sW[kbase +  7][wcol] = b1.w;
        sW[kbase +  8][wcol] = b2.x; sW[kbase +  9][wcol] = b2.y;
        sW[kbase + 10][wcol] = b2.z; sW[kbase + 11][wcol] = b2.w;
        sW[kbase + 12][wcol] = b3.x; sW[kbase + 13][wcol] = b3.y;
        sW[kbase + 14][wcol] = b3.z; sW[kbase + 15][wcol] = b3.w;

        __syncthreads();

        #pragma unroll
        for (int kk = 0; kk < KB; kk += 4) {
            float4 fq[8];
            #pragma unroll
            for (int i = 0; i < 8; ++i)
                fq[i] = *(const float4*)&sF[rg + 16 * i][kk];
            #pragma unroll
            for (int k4 = 0; k4 < 4; ++k4) {
                float4 w0 = *(const float4*)&sW[kk + k4][cg4];
                float4 w1 = *(const float4*)&sW[kk + k4][64 + cg4];
                #pragma unroll
                for (int i = 0; i < 8; ++i) {
                    float fv = (k4 == 0) ? fq[i].x :
                               (k4 == 1) ? fq[i].y :
                               (k4 == 2) ? fq[i].z : fq[i].w;
                    fma4(acc0[i], fv, w0);
                    fma4(acc1[i], fv, w1);
                }
            }
        }
    }

    const float4 bv0 = *(const float4*)&bias[cg4];
    const float4 bv1 = *(const float4*)&bias[64 + cg4];
    #pragma unroll
    for (int i = 0; i < 8; ++i) {
        const int row = row0 + rg + 16 * i;
        acc0[i].x += bv0.x; acc0[i].y += bv0.y; acc0[i].z += bv0.z; acc0[i].w += bv0.w;
        acc1[i].x += bv1.x; acc1[i].y += bv1.y; acc1[i].z += bv1.z; acc1[i].w += bv1.w;
        *(float4*)&z[(size_t)row * FEAT + cg4]      = acc0[i];
        *(float4*)&z[(size_t)row * FEAT + 64 + cg4] = acc1[i];
    }
}

// One wave per row: norms + dot + per-block partial sum.
__global__ __launch_bounds__(256) void combine(
    const float* __restrict__ z_s, const float* __restrict__ z_t,
    float* __restrict__ partials)
{
    const int wid  = threadIdx.x >> 6;
    const int lane = threadIdx.x & 63;
    const int row  = blockIdx.x * 4 + wid;

    const float2 zs = *(const float2*)&z_s[(size_t)row * FEAT + lane * 2];
    const float2 zt = *(const float2*)&z_t[(size_t)row * FEAT + lane * 2];

    float s2 = zs.x * zs.x + zs.y * zs.y;
    float t2 = zt.x * zt.x + zt.y * zt.y;
    float dt = zs.x * zt.x + zs.y * zt.y;

    #pragma unroll
    for (int off = 32; off; off >>= 1) {
        s2 += __shfl_xor(s2, off, 64);
        t2 += __shfl_xor(t2, off, 64);
        dt += __shfl_xor(dt, off, 64);
    }

    __shared__ float red[4];
    if (lane == 0) red[wid] = dt / sqrtf(s2 * t2);
    __syncthreads();
    if (threadIdx.x == 0)
        partials[blockIdx.x] = red[0] + red[1] + red[2] + red[3];
}

__global__ __launch_bounds__(256) void finalize(
    const float* __restrict__ partials, float* __restrict__ out)
{
    const int t = threadIdx.x;
    float v = 0.f;
    #pragma unroll
    for (int i = 0; i < 16; ++i) v += partials[t + i * 256];
    #pragma unroll
    for (int off = 32; off; off >>= 1) v += __shfl_xor(v, off, 64);

    __shared__ float red[4];
    if ((t & 63) == 0) red[t >> 6] = v;
    __syncthreads();
    if (t == 0) out[0] = -(red[0] + red[1] + red[2] + red[3]) / 16384.0f;
}

extern "C" void kernel_launch(void* const* d_in, const int* in_sizes, int n_in,
                              void* d_out, int out_size, void* d_ws, size_t ws_size,
                              hipStream_t stream)
{
    const float* f_s = (const float*)d_in[0];
    const float* f_t = (const float*)d_in[1];
    const float* W_s = (const float*)d_in[2];
    const float* b_s = (const float*)d_in[3];
    const float* W_t = (const float*)d_in[4];
    const float* b_t = (const float*)d_in[5];

    float* z_s      = (float*)d_ws;
    float* z_t      = z_s + (size_t)BROWS * FEAT;
    float* partials = z_t + (size_t)BROWS * FEAT;

    gemm_embed<<<256, 256, 0, stream>>>(f_s, W_s, b_s, f_t, W_t, b_t, z_s, z_t);
    combine<<<4096, 256, 0, stream>>>(z_s, z_t, partials);
    finalize<<<1, 256, 0, stream>>>(partials, (float*)d_out);
}

// Round 3
// 204.028 us; speedup vs baseline: 1.2053x; 1.2053x over previous
//
#include <hip/hip_runtime.h>
#include <math.h>

typedef __attribute__((ext_vector_type(8))) short bf16x8;
typedef __attribute__((ext_vector_type(8))) unsigned short u16x8;
typedef __attribute__((ext_vector_type(4))) float f32x4;

#define FEAT 128
#define KS   768
#define KT   1024
#define BM   64
#define KB   64
#define LDK  72   // padded LDS row (bf16 elems): 144 B stride -> 4-bank shift/row

__device__ __forceinline__ unsigned short f2bf(float f) {
    unsigned u = __float_as_uint(f);
    u += 0x7fff + ((u >> 16) & 1);   // RNE; inputs are well-scaled, no NaN/Inf
    return (unsigned short)(u >> 16);
}
__device__ __forceinline__ float bf2f(unsigned short h) {
    return __uint_as_float((unsigned)h << 16);
}

// Split W_s, W_t into bf16 hi/lo (same flat [FEAT][K] layout as source).
__global__ __launch_bounds__(256) void convert_w(
    const float* __restrict__ Ws, const float* __restrict__ Wt,
    unsigned short* __restrict__ WhiS, unsigned short* __restrict__ WloS,
    unsigned short* __restrict__ WhiT, unsigned short* __restrict__ WloT)
{
    const int NS = FEAT * KS;
    int e = blockIdx.x * 256 + threadIdx.x;
    if (e < NS) {
        float w = Ws[e];
        unsigned short h = f2bf(w);
        WhiS[e] = h;
        WloS[e] = f2bf(w - bf2f(h));
    } else {
        int e2 = e - NS;
        float w = Wt[e2];
        unsigned short h = f2bf(w);
        WhiT[e2] = h;
        WloT[e2] = f2bf(w - bf2f(h));
    }
}

// One block = 64 batch rows, BOTH embeddings (full FEAT=128), bf16x3 MFMA,
// fused bias + L2-norm + row-dot epilogue -> one partial per block.
// 512 threads = 8 waves in a 2(M) x 4(N) grid; per wave 32x32 out = 2x2 frags.
__global__ __launch_bounds__(512, 2) void gemm_fused(
    const float* __restrict__ f_s, const float* __restrict__ f_t,
    const unsigned short* __restrict__ WhiS, const unsigned short* __restrict__ WloS,
    const unsigned short* __restrict__ WhiT, const unsigned short* __restrict__ WloT,
    const float* __restrict__ b_s, const float* __restrict__ b_t,
    float* __restrict__ partials)
{
    __shared__ unsigned short sAhi[BM][LDK], sAlo[BM][LDK];
    __shared__ unsigned short sBhi[FEAT][LDK], sBlo[FEAT][LDK];
    __shared__ float sRed[64][4][3];

    const int tid  = threadIdx.x;
    const int lane = tid & 63;
    const int wv   = tid >> 6;
    const int wm   = wv >> 2;          // 0..1
    const int wn   = wv & 3;           // 0..3
    const int l15  = lane & 15;
    const int l4   = lane >> 4;
    const int row0 = blockIdx.x * BM;

    const int arow = tid >> 3;         // A staging: 64 rows x 8 k-segs
    const int ak8  = tid & 7;

    f32x4 accS[2][2], accT[2][2];
    #pragma unroll
    for (int m = 0; m < 2; ++m)
        #pragma unroll
        for (int n = 0; n < 2; ++n) {
            accS[m][n] = (f32x4){0.f, 0.f, 0.f, 0.f};
            accT[m][n] = (f32x4){0.f, 0.f, 0.f, 0.f};
        }

    #pragma unroll
    for (int ph = 0; ph < 2; ++ph) {
        const float*          f   = ph ? f_t  : f_s;
        const unsigned short* Whi = ph ? WhiT : WhiS;
        const unsigned short* Wlo = ph ? WloT : WloS;
        const int             K   = ph ? KT   : KS;
        f32x4* acc = ph ? &accT[0][0] : &accS[0][0];

        const float* fbase = f + (size_t)(row0 + arow) * K + ak8 * 8;

        for (int k0 = 0; k0 < K; k0 += KB) {
            // ---- prefetch globals before the barrier ----
            float4 a0 = *(const float4*)(fbase + k0);
            float4 a1 = *(const float4*)(fbase + k0 + 4);
            uint4 bh[2], bl[2];
            int brow[2], bk8[2];
            #pragma unroll
            for (int j = 0; j < 2; ++j) {
                int c = j * 512 + tid;           // 1024 chunks: [128 rows][8 segs]
                brow[j] = c >> 3; bk8[j] = c & 7;
                size_t off = (size_t)brow[j] * K + k0 + bk8[j] * 8;
                bh[j] = *(const uint4*)(Whi + off);
                bl[j] = *(const uint4*)(Wlo + off);
            }

            __syncthreads();   // previous tile fully consumed

            // ---- A: convert fp32 -> bf16 hi/lo, stage ----
            float av[8] = {a0.x, a0.y, a0.z, a0.w, a1.x, a1.y, a1.z, a1.w};
            u16x8 vh, vl;
            #pragma unroll
            for (int i = 0; i < 8; ++i) {
                unsigned short h = f2bf(av[i]);
                vh[i] = h;
                vl[i] = f2bf(av[i] - bf2f(h));
            }
            *(u16x8*)&sAhi[arow][ak8 * 8] = vh;
            *(u16x8*)&sAlo[arow][ak8 * 8] = vl;

            // ---- B: stage pre-split bf16 ----
            #pragma unroll
            for (int j = 0; j < 2; ++j) {
                *(uint4*)&sBhi[brow[j]][bk8[j] * 8] = bh[j];
                *(uint4*)&sBlo[brow[j]][bk8[j] * 8] = bl[j];
            }

            __syncthreads();

            // ---- MFMA: 2 k-steps of 32, 3-product bf16 emulation ----
            #pragma unroll
            for (int ks = 0; ks < 2; ++ks) {
                const int ka = ks * 32 + l4 * 8;
                bf16x8 ah[2], al[2], bhf[2], blf[2];
                #pragma unroll
                for (int m = 0; m < 2; ++m) {
                    int r = wm * 32 + m * 16 + l15;
                    ah[m] = *(const bf16x8*)&sAhi[r][ka];
                    al[m] = *(const bf16x8*)&sAlo[r][ka];
                }
                #pragma unroll
                for (int n = 0; n < 2; ++n) {
                    int cn = wn * 32 + n * 16 + l15;
                    bhf[n] = *(const bf16x8*)&sBhi[cn][ka];
                    blf[n] = *(const bf16x8*)&sBlo[cn][ka];
                }
                #pragma unroll
                for (int m = 0; m < 2; ++m)
                    #pragma unroll
                    for (int n = 0; n < 2; ++n) {
                        f32x4 c = acc[m * 2 + n];
                        c = __builtin_amdgcn_mfma_f32_16x16x32_bf16(ah[m], bhf[n], c, 0, 0, 0);
                        c = __builtin_amdgcn_mfma_f32_16x16x32_bf16(ah[m], blf[n], c, 0, 0, 0);
                        c = __builtin_amdgcn_mfma_f32_16x16x32_bf16(al[m], bhf[n], c, 0, 0, 0);
                        acc[m * 2 + n] = c;
                    }
            }
        }
    }

    // ---- bias ----
    #pragma unroll
    for (int n = 0; n < 2; ++n) {
        int col = wn * 32 + n * 16 + l15;
        float bsv = b_s[col], btv = b_t[col];
        #pragma unroll
        for (int m = 0; m < 2; ++m) {
            accS[m][n] += bsv;
            accT[m][n] += btv;
        }
    }

    // ---- fused epilogue: per-row s2/t2/dot, cross-lane + cross-wave reduce ----
    #pragma unroll
    for (int m = 0; m < 2; ++m) {
        #pragma unroll
        for (int r = 0; r < 4; ++r) {
            float s2 = accS[m][0][r] * accS[m][0][r] + accS[m][1][r] * accS[m][1][r];
            float t2 = accT[m][0][r] * accT[m][0][r] + accT[m][1][r] * accT[m][1][r];
            float dt = accS[m][0][r] * accT[m][0][r] + accS[m][1][r] * accT[m][1][r];
            #pragma unroll
            for (int d = 1; d < 16; d <<= 1) {
                s2 += __shfl_xor(s2, d, 64);
                t2 += __shfl_xor(t2, d, 64);
                dt += __shfl_xor(dt, d, 64);
            }
            if (l15 == 0) {
                int row = wm * 32 + m * 16 + l4 * 4 + r;
                sRed[row][wn][0] = s2;
                sRed[row][wn][1] = t2;
                sRed[row][wn][2] = dt;
            }
        }
    }
    __syncthreads();
    if (tid < 64) {
        float s2 = sRed[tid][0][0] + sRed[tid][1][0] + sRed[tid][2][0] + sRed[tid][3][0];
        float t2 = sRed[tid][0][1] + sRed[tid][1][1] + sRed[tid][2][1] + sRed[tid][3][1];
        float dt = sRed[tid][0][2] + sRed[tid][1][2] + sRed[tid][2][2] + sRed[tid][3][2];
        float v = dt / sqrtf(s2 * t2);
        #pragma unroll
        for (int d = 1; d < 64; d <<= 1) v += __shfl_xor(v, d, 64);
        if (tid == 0) partials[blockIdx.x] = v;
    }
}

__global__ __launch_bounds__(256) void finalize(
    const float* __restrict__ partials, float* __restrict__ out)
{
    const int tid = threadIdx.x;
    float v = partials[tid];
    #pragma unroll
    for (int d = 1; d < 64; d <<= 1) v += __shfl_xor(v, d, 64);
    __shared__ float r[4];
    if ((tid & 63) == 0) r[tid >> 6] = v;
    __syncthreads();
    if (tid == 0) out[0] = -(r[0] + r[1] + r[2] + r[3]) / 16384.0f;
}

extern "C" void kernel_launch(void* const* d_in, const int* in_sizes, int n_in,
                              void* d_out, int out_size, void* d_ws, size_t ws_size,
                              hipStream_t stream)
{
    const float* f_s = (const float*)d_in[0];
    const float* f_t = (const float*)d_in[1];
    const float* W_s = (const float*)d_in[2];
    const float* b_s = (const float*)d_in[3];
    const float* W_t = (const float*)d_in[4];
    const float* b_t = (const float*)d_in[5];

    unsigned char* ws = (unsigned char*)d_ws;
    unsigned short* WhiS = (unsigned short*)(ws);
    unsigned short* WloS = (unsigned short*)(ws + 196608);
    unsigned short* WhiT = (unsigned short*)(ws + 393216);
    unsigned short* WloT = (unsigned short*)(ws + 655360);
    float*          part = (float*)(ws + 917504);

    convert_w<<<896, 256, 0, stream>>>(W_s, W_t, WhiS, WloS, WhiT, WloT);
    gemm_fused<<<256, 512, 0, stream>>>(f_s, f_t, WhiS, WloS, WhiT, WloT,
                                        b_s, b_t, part);
    finalize<<<1, 256, 0, stream>>>(part, (float*)d_out);
}